// Round 5
// baseline (599.671 us; speedup 1.0000x reference)
//
#include <hip/hip_runtime.h>

#define D 256
#define NPATHS 4096
#define PLEN 64
#define NSTEPS (NPATHS * PLEN)   /* 262144 */
#define NNODES 10000

__device__ __forceinline__ void fma4(float4& acc, float s, const float4& w) {
    acc.x += s * w.x; acc.y += s * w.y; acc.z += s * w.z; acc.w += s * w.w;
}

// __builtin_nontemporal_load needs a native vector type, not HIP_vector_type.
typedef float fvec4 __attribute__((ext_vector_type(4)));
__device__ __forceinline__ float4 nt_load4(const float4* p) {
    fvec4 v = __builtin_nontemporal_load(reinterpret_cast<const fvec4*>(p));
    return make_float4(v.x, v.y, v.z, v.w);
}

// ---------------- K1: q = prev @ Wq  [NNODES, D] ----------------
// one wave per block, 16 rows/wave; A via wave-uniform scalar loads (s_load),
// W streamed coalesced (float4/lane = 4 owned columns). No LDS.
#define QR 16
__global__ __launch_bounds__(64) void k_query(const float* __restrict__ prev,
                                              const float* __restrict__ Wq,
                                              float* __restrict__ q) {
    const int lane = threadIdx.x;
    const int row0 = blockIdx.x * QR;          // 625 blocks, exact
    const float4* W4 = reinterpret_cast<const float4*>(Wq);   // [256][64]
    float4 acc[QR];
#pragma unroll
    for (int r = 0; r < QR; ++r) acc[r] = make_float4(0.f, 0.f, 0.f, 0.f);

    for (int k4 = 0; k4 < 64; ++k4) {
        float4 w0 = W4[(k4 * 4 + 0) * 64 + lane];
        float4 w1 = W4[(k4 * 4 + 1) * 64 + lane];
        float4 w2 = W4[(k4 * 4 + 2) * 64 + lane];
        float4 w3 = W4[(k4 * 4 + 3) * 64 + lane];
#pragma unroll
        for (int r = 0; r < QR; ++r) {
            float4 a = *reinterpret_cast<const float4*>(&prev[(size_t)(row0 + r) * D + k4 * 4]);
            fma4(acc[r], a.x, w0);
            fma4(acc[r], a.y, w1);
            fma4(acc[r], a.z, w2);
            fma4(acc[r], a.w, w3);
        }
    }
    float4* Q4 = reinterpret_cast<float4*>(q);
#pragma unroll
    for (int r = 0; r < QR; ++r) Q4[(size_t)(row0 + r) * 64 + lane] = acc[r];
}

// ---------------- K2: per-node histogram of unmasked steps ----------------
__global__ __launch_bounds__(256) void k_count(const int* __restrict__ mask,
                                               const int* __restrict__ nidx,
                                               int* __restrict__ counts) {
    const int step = blockIdx.x * 256 + threadIdx.x;
    if (step >= NSTEPS) return;
    if (!mask[step]) return;
    atomicAdd(&counts[nidx[step]], 1);
}

// ---------------- K3: exclusive scan of counts -> offsets (+cursor copy) ----
__global__ __launch_bounds__(256) void k_scan(const int* __restrict__ counts,
                                              int* __restrict__ offsets,
                                              int* __restrict__ cursor) {
    const int tid = threadIdx.x;
    const int lane = tid & 63;
    const int w = tid >> 6;
    const int CH = 40;  // 256*40 = 10240 >= NNODES
    const int base = tid * CH;
    int s = 0;
    for (int i = 0; i < CH; ++i) {
        int j = base + i;
        if (j < NNODES) s += counts[j];
    }
    int v = s;
    for (int d = 1; d < 64; d <<= 1) {
        int t = __shfl_up(v, d);
        if (lane >= d) v += t;
    }
    __shared__ int wsum[4];
    if (lane == 63) wsum[w] = v;
    __syncthreads();
    int woff = 0;
    for (int i = 0; i < w; ++i) woff += wsum[i];
    int run = woff + v - s;
    for (int i = 0; i < CH; ++i) {
        int j = base + i;
        if (j < NNODES) {
            offsets[j] = run;
            cursor[j] = run;
            run += counts[j];
        }
    }
    if (tid == 255) offsets[NNODES] = run;
}

// ---------------- K4: fill perm with unmasked step ids grouped by node ------
__global__ __launch_bounds__(256) void k_perm(const int* __restrict__ mask,
                                              const int* __restrict__ nidx,
                                              int* __restrict__ cursor,
                                              int* __restrict__ perm) {
    const int step = blockIdx.x * 256 + threadIdx.x;
    if (step >= NSTEPS) return;
    if (!mask[step]) return;
    const int node = nidx[step];
    int p = atomicAdd(&cursor[node], 1);
    perm[p] = step;
}

// ---------------- K5: wave-per-node online-softmax weighted accumulate ------
// perm chunk coalesced, step-ids via shfl, x-row loads depth-4 pipelined,
// nontemporal (x touched exactly once globally - don't thrash L2).
__global__ __launch_bounds__(256) void k_combine(const float* __restrict__ x,
                                                 const float* __restrict__ q,
                                                 const int* __restrict__ offsets,
                                                 const int* __restrict__ perm,
                                                 float* __restrict__ update) {
    const int wave = threadIdx.x >> 6;
    const int lane = threadIdx.x & 63;
    const int node = blockIdx.x * 4 + wave;
    if (node >= NNODES) return;
    const int off = offsets[node];
    const int cnt = offsets[node + 1] - off;

    const float4* x4 = reinterpret_cast<const float4*>(x);
    float4 qa = reinterpret_cast<const float4*>(q)[(size_t)node * 64 + lane];

    float4 acc = make_float4(0.f, 0.f, 0.f, 0.f);
    float m = -3.0e38f;
    float l = 0.f;

    for (int base = 0; base < cnt; base += 64) {
        const int lim = min(64, cnt - base);
        int myperm = perm[off + base + lane];  // coalesced; tail lanes unused

        float4 xs[4];
#pragma unroll
        for (int j = 0; j < 4; ++j) {
            if (j < lim) {
                int sj = __shfl(myperm, j);
                xs[j] = nt_load4(&x4[(size_t)sj * 64 + lane]);
            }
        }
        for (int i = 0; i < lim; ++i) {
            float4 cur = xs[i & 3];
            if (i + 4 < lim) {
                int sn = __shfl(myperm, i + 4);
                xs[i & 3] = nt_load4(&x4[(size_t)sn * 64 + lane]);
            }
            float s = cur.x * qa.x + cur.y * qa.y + cur.z * qa.z + cur.w * qa.w;
            s += __shfl_xor(s, 32);
            s += __shfl_xor(s, 16);
            s += __shfl_xor(s, 8);
            s += __shfl_xor(s, 4);
            s += __shfl_xor(s, 2);
            s += __shfl_xor(s, 1);
            s *= 0.0625f;  // 1/sqrt(256)

            float mn = fmaxf(m, s);
            float scale = __expf(m - mn);  // first iter: exp(-huge)=0
            float wgt = __expf(s - mn);
            l = l * scale + wgt;
            acc.x = acc.x * scale + wgt * cur.x;
            acc.y = acc.y * scale + wgt * cur.y;
            acc.z = acc.z * scale + wgt * cur.z;
            acc.w = acc.w * scale + wgt * cur.w;
            m = mn;
        }
    }

    const float inv = 1.f / fmaxf(l, 1e-9f);  // cnt==0: acc=0 -> output 0
    float4 o = make_float4(acc.x * inv, acc.y * inv, acc.z * inv, acc.w * inv);
    reinterpret_cast<float4*>(update)[(size_t)node * 64 + lane] = o;
}

// ---------------- K6: gated blend ----------------
// scalar-broadcast GEMV, 16 rows/wave; K=512 in two halves.
#define GR 16
__global__ __launch_bounds__(64) void k_gate(const float* __restrict__ prev,
                                             const float* __restrict__ update,
                                             const float* __restrict__ gW,
                                             const float* __restrict__ gb,
                                             float* __restrict__ out) {
    const int lane = threadIdx.x;
    const int row0 = blockIdx.x * GR;          // 625 blocks, exact
    const float4* W4 = reinterpret_cast<const float4*>(gW);   // [512][64]
    float4 acc[GR];
#pragma unroll
    for (int r = 0; r < GR; ++r) acc[r] = make_float4(0.f, 0.f, 0.f, 0.f);

    for (int k4 = 0; k4 < 64; ++k4) {
        float4 w0 = W4[(k4 * 4 + 0) * 64 + lane];
        float4 w1 = W4[(k4 * 4 + 1) * 64 + lane];
        float4 w2 = W4[(k4 * 4 + 2) * 64 + lane];
        float4 w3 = W4[(k4 * 4 + 3) * 64 + lane];
#pragma unroll
        for (int r = 0; r < GR; ++r) {
            float4 a = *reinterpret_cast<const float4*>(&prev[(size_t)(row0 + r) * D + k4 * 4]);
            fma4(acc[r], a.x, w0);
            fma4(acc[r], a.y, w1);
            fma4(acc[r], a.z, w2);
            fma4(acc[r], a.w, w3);
        }
    }
    for (int k4 = 0; k4 < 64; ++k4) {
        float4 w0 = W4[(256 + k4 * 4 + 0) * 64 + lane];
        float4 w1 = W4[(256 + k4 * 4 + 1) * 64 + lane];
        float4 w2 = W4[(256 + k4 * 4 + 2) * 64 + lane];
        float4 w3 = W4[(256 + k4 * 4 + 3) * 64 + lane];
#pragma unroll
        for (int r = 0; r < GR; ++r) {
            float4 a = *reinterpret_cast<const float4*>(&update[(size_t)(row0 + r) * D + k4 * 4]);
            fma4(acc[r], a.x, w0);
            fma4(acc[r], a.y, w1);
            fma4(acc[r], a.z, w2);
            fma4(acc[r], a.w, w3);
        }
    }
    const float4* P4 = reinterpret_cast<const float4*>(prev);
    const float4* U4 = reinterpret_cast<const float4*>(update);
    const float4 b4 = reinterpret_cast<const float4*>(gb)[lane];
    float4* O4 = reinterpret_cast<float4*>(out);
#pragma unroll
    for (int r = 0; r < GR; ++r) {
        const size_t ri = (size_t)(row0 + r) * 64 + lane;
        float4 p = P4[ri];
        float4 u = U4[ri];
        float gx = 1.f / (1.f + __expf(-(acc[r].x + b4.x)));
        float gy = 1.f / (1.f + __expf(-(acc[r].y + b4.y)));
        float gz = 1.f / (1.f + __expf(-(acc[r].z + b4.z)));
        float gw = 1.f / (1.f + __expf(-(acc[r].w + b4.w)));
        float4 o;
        o.x = gx * p.x + (1.f - gx) * u.x;
        o.y = gy * p.y + (1.f - gy) * u.y;
        o.z = gz * p.z + (1.f - gz) * u.z;
        o.w = gw * p.w + (1.f - gw) * u.w;
        O4[ri] = o;
    }
}

extern "C" void kernel_launch(void* const* d_in, const int* in_sizes, int n_in,
                              void* d_out, int out_size, void* d_ws, size_t ws_size,
                              hipStream_t stream) {
    const float* enc   = (const float*)d_in[0];  // [4096,64,256]
    const int*   mask  = (const int*)d_in[1];    // [4096,64]
    const int*   nidx  = (const int*)d_in[2];    // [4096,64]
    const float* prev  = (const float*)d_in[3];  // [10000,256]
    const float* Wq    = (const float*)d_in[4];  // [256,256]
    const float* gW    = (const float*)d_in[5];  // [512,256]
    const float* gb    = (const float*)d_in[6];  // [256]
    float* out = (float*)d_out;

    // workspace layout (256B-aligned)
    char* ws = (char*)d_ws;
    float* q       = (float*)(ws + 0);           // 10,240,000 B
    int*   counts  = (int*)  (ws + 10240000);    //     40,000 B
    int*   offsets = (int*)  (ws + 10280192);    //     40,004 B
    int*   cursor  = (int*)  (ws + 10320640);    //     40,000 B
    int*   perm    = (int*)  (ws + 10360832);    //  1,048,576 B
    float* update  = (float*)(ws + 11409408);    // 10,240,000 B

    (void)hipMemsetAsync(counts, 0, NNODES * sizeof(int), stream);

    k_query<<<NNODES / QR, 64, 0, stream>>>(prev, Wq, q);
    k_count<<<NSTEPS / 256, 256, 0, stream>>>(mask, nidx, counts);
    k_scan<<<1, 256, 0, stream>>>(counts, offsets, cursor);
    k_perm<<<NSTEPS / 256, 256, 0, stream>>>(mask, nidx, cursor, perm);
    k_combine<<<(NNODES + 3) / 4, 256, 0, stream>>>(enc, q, offsets, perm, update);
    k_gate<<<NNODES / GR, 64, 0, stream>>>(prev, update, gW, gb, out);
}